// Round 1
// baseline (11383.475 us; speedup 1.0000x reference)
//
#include <hip/hip_runtime.h>
#include <math.h>

#define N_NODES 50000
#define N_EDGES 500000
#define H 128
#define NL 3
#define TE 64
#define TN 64
#define KC 32

__global__ void k_deg(const int* __restrict__ dst, float* __restrict__ deg) {
  int e = blockIdx.x * blockDim.x + threadIdx.x;
  if (e < N_EDGES) atomicAdd(&deg[dst[e]], 1.0f);
}

__global__ void k_inv(float* __restrict__ d) {
  int i = blockIdx.x * blockDim.x + threadIdx.x;
  if (i < N_NODES) d[i] = 1.0f / fmaxf(d[i], 1.0f);
}

// inner microkernel: C[64 edges][128 feats] += A_chunk @ B_chunk
// thread (eg=tid>>5, fg=tid&31) owns rows eg*8..+7, cols fg*4..+3
#define GEMM_INNER(SRC_A, ASTRIDE, AOFF, ACCV)                                 \
  _Pragma("unroll")                                                            \
  for (int k = 0; k < KC; k += 4) {                                            \
    float4 b0 = *(float4*)&sB[(k + 0) * 128 + fg * 4];                         \
    float4 b1 = *(float4*)&sB[(k + 1) * 128 + fg * 4];                         \
    float4 b2 = *(float4*)&sB[(k + 2) * 128 + fg * 4];                         \
    float4 b3 = *(float4*)&sB[(k + 3) * 128 + fg * 4];                         \
    const float *bp0 = &b0.x, *bp1 = &b1.x, *bp2 = &b2.x, *bp3 = &b3.x;        \
    _Pragma("unroll")                                                          \
    for (int e = 0; e < 8; ++e) {                                              \
      float4 a = *(float4*)&SRC_A[(eg * 8 + e) * ASTRIDE + (AOFF) + k];        \
      _Pragma("unroll")                                                        \
      for (int f = 0; f < 4; ++f)                                              \
        ACCV[e][f] += a.x * bp0[f] + a.y * bp1[f] + a.z * bp2[f] + a.w * bp3[f]; \
    }                                                                          \
  }

__launch_bounds__(256, 2)
__global__ void k_edge(const float* __restrict__ x,
                       const float* __restrict__ pos,
                       const float* __restrict__ eattr,
                       const int* __restrict__ srcI,
                       const int* __restrict__ dstI,
                       const float* __restrict__ mW1, const float* __restrict__ mb1,
                       const float* __restrict__ mW2, const float* __restrict__ mb2,
                       const float* __restrict__ aW1, const float* __restrict__ ab1,
                       const float* __restrict__ aW2, const float* __restrict__ ab2,
                       float* __restrict__ intra,
                       float* __restrict__ pdelta,
                       int do_intra)
{
  __shared__ float sA[TE * KC];     // 8 KB staging (gathered input chunk)
  __shared__ float sB[KC * 128];    // 16 KB staging (weight chunk)
  __shared__ float sHM[TE * 128];   // 32 KB: h1, then m
  __shared__ int sSrc[TE];
  __shared__ int sDst[TE];
  __shared__ float sW[TE];

  const int tid = threadIdx.x;
  const int e0 = blockIdx.x * TE;
  if (tid < TE) {
    int ec = min(e0 + tid, N_EDGES - 1);
    sSrc[tid] = srcI[ec];
    sDst[tid] = dstI[ec];
  }
  __syncthreads();

  const int fg = tid & 31;
  const int eg = tid >> 5;

  float acc[8][4];
#pragma unroll
  for (int e = 0; e < 8; ++e)
#pragma unroll
    for (int f = 0; f < 4; ++f) acc[e][f] = 0.0f;

  // ---- GEMM1: concat(x[dst], x[src], eattr) [TE,384] @ mW1 [384,128] ----
  for (int c = 0; c < 384 / KC; ++c) {
#pragma unroll
    for (int i = 0; i < (TE * KC / 4) / 256; ++i) {
      int flat = tid + i * 256;
      int e = flat / (KC / 4);
      int q = flat % (KC / 4);
      int col = c * KC + q * 4;
      const float* rp;
      if (col < H)            rp = x + (size_t)sDst[e] * H + col;
      else if (col < 2 * H)   rp = x + (size_t)sSrc[e] * H + (col - H);
      else                    rp = eattr + (size_t)min(e0 + e, N_EDGES - 1) * H + (col - 2 * H);
      *(float4*)&sA[e * KC + q * 4] = *(const float4*)rp;
    }
#pragma unroll
    for (int i = 0; i < (KC * 128 / 4) / 256; ++i) {
      int flat = tid + i * 256;
      int r = flat / 32, cq = flat % 32;
      *(float4*)&sB[r * 128 + cq * 4] =
          *(const float4*)&mW1[(size_t)(c * KC + r) * 128 + cq * 4];
    }
    __syncthreads();
    GEMM_INNER(sA, KC, 0, acc)
    __syncthreads();
  }

  // h1 = relu(acc + mb1) -> sHM
  {
    float4 bb = *(const float4*)&mb1[fg * 4];
    const float* bp = &bb.x;
#pragma unroll
    for (int e = 0; e < 8; ++e)
#pragma unroll
      for (int f = 0; f < 4; ++f) {
        sHM[(eg * 8 + e) * 128 + fg * 4 + f] = fmaxf(acc[e][f] + bp[f], 0.0f);
        acc[e][f] = 0.0f;
      }
  }
  __syncthreads();

  // ---- GEMM2: h1 [TE,128] @ mW2 [128,128] ----
  for (int c = 0; c < 128 / KC; ++c) {
#pragma unroll
    for (int i = 0; i < (KC * 128 / 4) / 256; ++i) {
      int flat = tid + i * 256;
      int r = flat / 32, cq = flat % 32;
      *(float4*)&sB[r * 128 + cq * 4] =
          *(const float4*)&mW2[(size_t)(c * KC + r) * 128 + cq * 4];
    }
    __syncthreads();
    GEMM_INNER(sHM, 128, c * KC, acc)
    __syncthreads();
  }

  // m = acc + mb2 -> sHM (overwrite h1; all GEMM2 reads are done)
  {
    float4 bb = *(const float4*)&mb2[fg * 4];
    const float* bp = &bb.x;
#pragma unroll
    for (int e = 0; e < 8; ++e)
#pragma unroll
      for (int f = 0; f < 4; ++f)
        sHM[(eg * 8 + e) * 128 + fg * 4 + f] = acc[e][f] + bp[f];
  }

  // ---- acc MLP: w = relu(m @ aW1 + ab1) @ aW2 + ab2 ----
  float wacc[8];
#pragma unroll
  for (int e = 0; e < 8; ++e) wacc[e] = 0.0f;

  for (int half = 0; half < 2; ++half) {
#pragma unroll
    for (int e = 0; e < 8; ++e)
#pragma unroll
      for (int f = 0; f < 4; ++f) acc[e][f] = 0.0f;
    for (int c = 0; c < 128 / KC; ++c) {
#pragma unroll
      for (int i = 0; i < (KC * 128 / 4) / 256; ++i) {
        int flat = tid + i * 256;
        int r = flat / 32, cq = flat % 32;
        *(float4*)&sB[r * 128 + cq * 4] =
            *(const float4*)&aW1[(size_t)(c * KC + r) * 256 + half * 128 + cq * 4];
      }
      __syncthreads();
      GEMM_INNER(sHM, 128, c * KC, acc)
      __syncthreads();
    }
    float4 bb = *(const float4*)&ab1[half * 128 + fg * 4];
    float4 w2 = *(const float4*)&aW2[half * 128 + fg * 4];
    const float* bp = &bb.x;
    const float* wp = &w2.x;
#pragma unroll
    for (int e = 0; e < 8; ++e)
#pragma unroll
      for (int f = 0; f < 4; ++f)
        wacc[e] += fmaxf(acc[e][f] + bp[f], 0.0f) * wp[f];
  }

  // reduce wacc across the 32 fg lanes (masks < 32 stay in each half-wave)
#pragma unroll
  for (int m = 16; m >= 1; m >>= 1)
#pragma unroll
    for (int e = 0; e < 8; ++e)
      wacc[e] += __shfl_xor(wacc[e], m, 64);
  if (fg == 0) {
#pragma unroll
    for (int e = 0; e < 8; ++e) sW[eg * 8 + e] = wacc[e] + ab2[0];
  }
  __syncthreads();

  // ---- scatter: pos_delta and intra ----
  if (tid < TE) {
    int e = e0 + tid;
    if (e < N_EDGES) {
      int s = sSrc[tid], d = sDst[tid];
      float rx = pos[s * 3 + 0] - pos[d * 3 + 0];
      float ry = pos[s * 3 + 1] - pos[d * 3 + 1];
      float rz = pos[s * 3 + 2] - pos[d * 3 + 2];
      float dist = sqrtf(rx * rx + ry * ry + rz * rz);
      float cf = sW[tid] / dist;
      atomicAdd(&pdelta[d * 3 + 0], cf * rx);
      atomicAdd(&pdelta[d * 3 + 1], cf * ry);
      atomicAdd(&pdelta[d * 3 + 2], cf * rz);
    }
  }
  if (do_intra) {
    int nv = min(N_EDGES - e0, TE);
#pragma unroll
    for (int i = 0; i < (TE * 128) / 256; ++i) {
      int flat = tid + i * 256;
      int e = flat >> 7, f = flat & 127;
      if (e < nv)
        atomicAdd(&intra[(size_t)sDst[e] * H + f], sHM[e * 128 + f]);
    }
  }
}

__launch_bounds__(256, 2)
__global__ void k_node(const float* __restrict__ x,
                       const float* __restrict__ intra,
                       const float* __restrict__ invd,
                       const float* __restrict__ nW1, const float* __restrict__ nb1,
                       const float* __restrict__ nW2, const float* __restrict__ nb2,
                       const float* __restrict__ pos_in,
                       const float* __restrict__ pdelta,
                       float* __restrict__ x_out,
                       float* __restrict__ pos_out,
                       int compute_x)
{
  __shared__ float sA[TN * KC];     // 8 KB
  __shared__ float sB[KC * 128];    // 16 KB
  __shared__ float sH[TN * 128];    // 32 KB (one hidden half at a time)
  const int tid = threadIdx.x;
  const int n0 = blockIdx.x * TN;

  if (tid < 192) {
    int n = n0 + tid / 3, cc = tid % 3;
    if (n < N_NODES)
      pos_out[n * 3 + cc] = pos_in[n * 3 + cc] + pdelta[n * 3 + cc] * invd[n];
  }
  if (!compute_x) return;

  const int fg = tid & 31, eg = tid >> 5;
  float xacc[8][4], acc[8][4];
#pragma unroll
  for (int e = 0; e < 8; ++e)
#pragma unroll
    for (int f = 0; f < 4; ++f) xacc[e][f] = 0.0f;

  for (int half = 0; half < 2; ++half) {
#pragma unroll
    for (int e = 0; e < 8; ++e)
#pragma unroll
      for (int f = 0; f < 4; ++f) acc[e][f] = 0.0f;
    // GEMM_A: concat(x, intra*invd) [TN,256] @ nW1[:, half*128..]
    for (int c = 0; c < 256 / KC; ++c) {
#pragma unroll
      for (int i = 0; i < (TN * KC / 4) / 256; ++i) {
        int flat = tid + i * 256;
        int e = flat / (KC / 4), q = flat % (KC / 4);
        int col = c * KC + q * 4;
        int n = min(n0 + e, N_NODES - 1);
        float4 v;
        if (col < H) {
          v = *(const float4*)&x[(size_t)n * H + col];
        } else {
          v = *(const float4*)&intra[(size_t)n * H + (col - H)];
          float iv = invd[n];
          v.x *= iv; v.y *= iv; v.z *= iv; v.w *= iv;
        }
        *(float4*)&sA[e * KC + q * 4] = v;
      }
#pragma unroll
      for (int i = 0; i < (KC * 128 / 4) / 256; ++i) {
        int flat = tid + i * 256;
        int r = flat / 32, cq = flat % 32;
        *(float4*)&sB[r * 128 + cq * 4] =
            *(const float4*)&nW1[(size_t)(c * KC + r) * 256 + half * 128 + cq * 4];
      }
      __syncthreads();
      GEMM_INNER(sA, KC, 0, acc)
      __syncthreads();
    }
    // relu + bias -> sH (this half's hidden)
    {
      float4 bb = *(const float4*)&nb1[half * 128 + fg * 4];
      const float* bp = &bb.x;
#pragma unroll
      for (int e = 0; e < 8; ++e)
#pragma unroll
        for (int f = 0; f < 4; ++f)
          sH[(eg * 8 + e) * 128 + fg * 4 + f] = fmaxf(acc[e][f] + bp[f], 0.0f);
    }
    // GEMM_B partial: sH [TN,128] @ nW2[half*128.., :]
    for (int c = 0; c < 128 / KC; ++c) {
#pragma unroll
      for (int i = 0; i < (KC * 128 / 4) / 256; ++i) {
        int flat = tid + i * 256;
        int r = flat / 32, cq = flat % 32;
        *(float4*)&sB[r * 128 + cq * 4] =
            *(const float4*)&nW2[(size_t)(half * 128 + c * KC + r) * 128 + cq * 4];
      }
      __syncthreads();
      GEMM_INNER(sH, 128, c * KC, xacc)
      __syncthreads();
    }
  }
  // x_out = xacc + nb2
  {
    float4 bb = *(const float4*)&nb2[fg * 4];
    const float* bp = &bb.x;
#pragma unroll
    for (int e = 0; e < 8; ++e) {
      int n = n0 + eg * 8 + e;
      if (n < N_NODES) {
        float4 o;
        o.x = xacc[e][0] + bp[0];
        o.y = xacc[e][1] + bp[1];
        o.z = xacc[e][2] + bp[2];
        o.w = xacc[e][3] + bp[3];
        *(float4*)&x_out[(size_t)n * H + fg * 4] = o;
      }
    }
  }
}

extern "C" void kernel_launch(void* const* d_in, const int* in_sizes, int n_in,
                              void* d_out, int out_size, void* d_ws, size_t ws_size,
                              hipStream_t stream) {
  const float* x0    = (const float*)d_in[0];
  const int*   eidx  = (const int*)d_in[1];
  const float* eattr = (const float*)d_in[2];
  const float* pos0  = (const float*)d_in[3];
  const float* mW1 = (const float*)d_in[4];
  const float* mb1 = (const float*)d_in[5];
  const float* mW2 = (const float*)d_in[6];
  const float* mb2 = (const float*)d_in[7];
  const float* aW1 = (const float*)d_in[8];
  const float* ab1 = (const float*)d_in[9];
  const float* aW2 = (const float*)d_in[10];
  const float* ab2 = (const float*)d_in[11];
  const float* nW1 = (const float*)d_in[12];
  const float* nb1 = (const float*)d_in[13];
  const float* nW2 = (const float*)d_in[14];
  const float* nb2 = (const float*)d_in[15];
  const int* srcI = eidx;
  const int* dstI = eidx + N_EDGES;

  float* ws = (float*)d_ws;
  float* invd   = ws;                          // N
  float* pdelta = invd + N_NODES;              // 3N
  float* pos_a  = pdelta + 3 * N_NODES;        // 3N
  float* pos_b  = pos_a + 3 * N_NODES;         // 3N
  float* intra  = pos_b + 3 * N_NODES;         // N*H
  float* x_a    = intra + (size_t)N_NODES * H; // N*H
  float* x_b    = x_a + (size_t)N_NODES * H;   // N*H

  hipMemsetAsync(invd, 0, N_NODES * sizeof(float), stream);
  k_deg<<<(N_EDGES + 255) / 256, 256, 0, stream>>>(dstI, invd);
  k_inv<<<(N_NODES + 255) / 256, 256, 0, stream>>>(invd);

  const float* xc = x0;
  const float* pc = pos0;
  float* pos_out_final = (float*)d_out;

  for (int l = 0; l < NL; ++l) {
    int last = (l == NL - 1);
    hipMemsetAsync(pdelta, 0, 3 * N_NODES * sizeof(float), stream);
    if (!last)
      hipMemsetAsync(intra, 0, (size_t)N_NODES * H * sizeof(float), stream);

    k_edge<<<(N_EDGES + TE - 1) / TE, 256, 0, stream>>>(
        xc, pc, eattr, srcI, dstI,
        mW1 + (size_t)l * 384 * 128, mb1 + (size_t)l * 128,
        mW2 + (size_t)l * 128 * 128, mb2 + (size_t)l * 128,
        aW1 + (size_t)l * 128 * 256, ab1 + (size_t)l * 256,
        aW2 + (size_t)l * 256, ab2 + l,
        intra, pdelta, last ? 0 : 1);

    float* pn = last ? pos_out_final : (l == 0 ? pos_a : pos_b);
    float* xn = (l == 0) ? x_a : x_b;
    k_node<<<(N_NODES + TN - 1) / TN, 256, 0, stream>>>(
        xc, intra, invd,
        nW1 + (size_t)l * 256 * 256, nb1 + (size_t)l * 256,
        nW2 + (size_t)l * 256 * 128, nb2 + (size_t)l * 128,
        pc, pdelta, xn, pn, last ? 0 : 1);

    xc = xn;
    pc = pn;
  }
}